// Round 3
// baseline (5429.318 us; speedup 1.0000x reference)
//
#include <hip/hip_runtime.h>

#define NN 50000
#define NE 200000
#define NG 512
#define FN 64
#define FE 16
#define FE2 32
#define H 32
#define NL 3
#define EPSV 1e-5f

// ---------------- prep: repack W_nn[l][kf][i*32+o] -> Wt2[l][cb][i][c'] ----------------
// column c = cb*128 + c' indexes the flattened (kf,o) pair: kf = c>>5, o = c&31.
// Wt2 slice [cb] is a contiguous 32x128 (16 KB) block; stage-pairs (2 cb) are contiguous 32 KB.
__global__ void k_prep_wt(const float* __restrict__ Wnn, float* __restrict__ Wt2) {
    int idx = blockIdx.x * 256 + threadIdx.x;
    if (idx >= NL * 8 * 32 * 128) return;
    int cp = idx & 127;
    int i  = (idx >> 7) & 31;
    int cb = (idx >> 12) & 7;
    int l  = idx >> 15;
    int c  = cb * 128 + cp;
    int kf = c >> 5, o = c & 31;
    Wt2[idx] = Wnn[((size_t)l * 32 + kf) * 1024 + i * 32 + o];
}

// ---------------- node embedding: h = x @ W_node + b_node ----------------
__global__ void k_node_emb(const float* __restrict__ x, const float* __restrict__ W,
                           const float* __restrict__ b, float* __restrict__ h) {
    __shared__ float sW[FN * H];
    int t = threadIdx.x;
    for (int j = t; j < FN * H; j += 256) sW[j] = W[j];
    __syncthreads();
    int node = blockIdx.x * 8 + (t >> 5);
    int o = t & 31;
    if (node >= NN) return;
    const float* xr = x + node * FN;
    float acc = b[o];
#pragma unroll 16
    for (int i = 0; i < FN; i++) acc += xr[i] * sW[i * H + o];
    h[node * H + o] = acc;
}

// ---------------- edge embedding: ea = edge_attr @ W_edge + b_edge ----------------
__global__ void k_edge_emb(const float* __restrict__ eattr, const float* __restrict__ W,
                           const float* __restrict__ b, float* __restrict__ ea) {
    __shared__ float sW[FE * FE2];
    int t = threadIdx.x;
    for (int j = t; j < FE * FE2; j += 256) sW[j] = W[j];
    __syncthreads();
    int e = blockIdx.x * 8 + (t >> 5);
    int o = t & 31;
    if (e >= NE) return;
    const float* er = eattr + e * FE;
    float acc = b[o];
#pragma unroll
    for (int i = 0; i < FE; i++) acc += er[i] * sW[i * FE2 + o];
    ea[e * FE2 + o] = acc;
}

// ---------------- T = h @ Wt_l  (M=NN, K=32, Ncols=1024) ----------------
// v3: fat blocks. 512 threads, 64-node x 1024-col tile per block.
// Wt (128 KB) streamed through LDS in 4 stages of 32 KB (2 cb slices each).
// Per thread: acc[2][4][4], 4096 FMAs, h-tile reused across both cb slices.
__global__ __launch_bounds__(512) void k_gemm_T(const float* __restrict__ h,
                                                const float* __restrict__ Wt2l,
                                                float* __restrict__ T) {
    __shared__ __align__(16) float sh[64][36];   // 64 nodes x 32, padded (144 B rows)
    __shared__ float4 sW[2048];                  // 2 cb slices: [cbl][i][tc], 32 KB
    int t = threadIdx.x;
    int nb = blockIdx.x * 64;
    int tc = t & 31;
    int tr = t >> 5;                             // 0..15, handles nodes tr*4..tr*4+3

    // stage h tile: 64 nodes x 32 floats = 512 float4, one per thread
    {
        int node = t >> 3, q = t & 7;
        int gn = nb + node;
        float4 v = make_float4(0.f, 0.f, 0.f, 0.f);
        if (gn < NN) v = *(const float4*)(h + (size_t)gn * H + q * 4);
        *(float4*)&sh[node][q * 4] = v;
    }

    for (int s = 0; s < 4; s++) {
        const float4* wsrc = (const float4*)(Wt2l + (size_t)s * 8192);
        __syncthreads();                          // prev readers done (and sh ready at s=0)
        for (int j = t; j < 2048; j += 512) sW[j] = wsrc[j];
        __syncthreads();

        float acc[2][4][4];
#pragma unroll
        for (int cbl = 0; cbl < 2; cbl++)
#pragma unroll
            for (int r = 0; r < 4; r++)
#pragma unroll
                for (int j = 0; j < 4; j++) acc[cbl][r][j] = 0.f;

#pragma unroll
        for (int kk = 0; kk < 32; kk += 4) {
            float4 ha[4];
#pragma unroll
            for (int r = 0; r < 4; r++) ha[r] = *(const float4*)&sh[tr * 4 + r][kk];
#pragma unroll
            for (int cbl = 0; cbl < 2; cbl++) {
#pragma unroll
                for (int q = 0; q < 4; q++) {
                    float4 w = sW[cbl * 1024 + (kk + q) * 32 + tc];
#pragma unroll
                    for (int r = 0; r < 4; r++) {
                        float hv = (q == 0) ? ha[r].x : (q == 1) ? ha[r].y
                                 : (q == 2) ? ha[r].z : ha[r].w;
                        acc[cbl][r][0] += hv * w.x;
                        acc[cbl][r][1] += hv * w.y;
                        acc[cbl][r][2] += hv * w.z;
                        acc[cbl][r][3] += hv * w.w;
                    }
                }
            }
        }

#pragma unroll
        for (int cbl = 0; cbl < 2; cbl++) {
#pragma unroll
            for (int r = 0; r < 4; r++) {
                int node = nb + tr * 4 + r;
                if (node < NN) {
                    float4 v = make_float4(acc[cbl][r][0], acc[cbl][r][1],
                                           acc[cbl][r][2], acc[cbl][r][3]);
                    *(float4*)(T + (size_t)node * 1024 + (s * 2 + cbl) * 128 + tc * 4) = v;
                }
            }
        }
    }
}

// ---------------- node linear: z = h@W_root + b_conv ; u = h@Bnn ----------------
__global__ void k_node_lin(const float* __restrict__ h, const float* __restrict__ Wr,
                           const float* __restrict__ bc, const float* __restrict__ bnn,
                           float* __restrict__ z, float* __restrict__ u) {
    __shared__ float sWr[H * H];
    __shared__ float sBn[H * H];
    int t = threadIdx.x;
    for (int j = t; j < H * H; j += 256) { sWr[j] = Wr[j]; sBn[j] = bnn[j]; }
    __syncthreads();
    int node = blockIdx.x * 8 + (t >> 5);
    int o = t & 31;
    if (node >= NN) return;
    const float* hr = h + node * H;
    float a = bc[o], bacc = 0.f;
#pragma unroll
    for (int i = 0; i < H; i++) {
        float hv = hr[i];
        a += hv * sWr[i * H + o];
        bacc += hv * sBn[i * H + o];
    }
    z[node * H + o] = a;
    u[node * H + o] = bacc;
}

// ---------------- edge message: m = u_src + ea_e . T_src ; atomic into agg[dst] ----------------
__global__ void k_edge_msg(const float* __restrict__ ea, const float* __restrict__ T,
                           const float* __restrict__ u, const int* __restrict__ src,
                           const int* __restrict__ dst, float* __restrict__ agg) {
    __shared__ float sea[8][32];
    int t = threadIdx.x;
    int eb = blockIdx.x * 8;
    {
        int e = eb + (t >> 5);
        if (e < NE) sea[t >> 5][t & 31] = ea[e * FE2 + (t & 31)];
    }
    __syncthreads();
    int e = eb + (t >> 5);
    int o = t & 31;
    if (e >= NE) return;
    int s = src[e], d = dst[e];
    const float* Tr = T + (size_t)s * 1024;
    float m = u[s * H + o];
    const float* sr = sea[t >> 5];
#pragma unroll
    for (int k = 0; k < 32; k++) m += sr[k] * Tr[k * 32 + o];
    atomicAdd(&agg[d * H + o], m);
}

// ---------------- z += agg ; accumulate per-channel sum & sumsq ----------------
__global__ void k_add_stats(float* __restrict__ z, const float* __restrict__ agg,
                            float* __restrict__ stats) {
    __shared__ float red[256];
    int t = threadIdx.x;
    float s = 0.f, s2 = 0.f;
    for (size_t idx = (size_t)blockIdx.x * 256 + t; idx < (size_t)NN * H;
         idx += (size_t)gridDim.x * 256) {
        float v = z[idx] + agg[idx];
        z[idx] = v;
        s += v;
        s2 += v * v;
    }
    red[t] = s;
    __syncthreads();
    for (int st = 128; st >= 32; st >>= 1) {
        if (t < st) red[t] += red[t + st];
        __syncthreads();
    }
    if (t < 32) atomicAdd(&stats[t], red[t]);
    __syncthreads();
    red[t] = s2;
    __syncthreads();
    for (int st = 128; st >= 32; st >>= 1) {
        if (t < st) red[t] += red[t + st];
        __syncthreads();
    }
    if (t < 32) atomicAdd(&stats[32 + t], red[t]);
}

// ---------------- BN apply + ReLU ----------------
__global__ void k_bn_apply(const float* __restrict__ z, const float* __restrict__ stats,
                           const float* __restrict__ gamma, const float* __restrict__ beta,
                           float* __restrict__ h) {
    int idx = blockIdx.x * 256 + threadIdx.x;
    if (idx >= NN * H) return;
    int o = idx & 31;
    const float invn = 1.0f / (float)NN;
    float mu = stats[o] * invn;
    float var = stats[32 + o] * invn - mu * mu;
    float v = (z[idx] - mu) * rsqrtf(var + EPSV) * gamma[o] + beta[o];
    h[idx] = v > 0.f ? v : 0.f;
}

// ---------------- pool: segment sums over graphs ----------------
__global__ void k_pool(const float* __restrict__ h, const int* __restrict__ batch,
                       float* __restrict__ gsum, float* __restrict__ cnt) {
    int idx = blockIdx.x * 256 + threadIdx.x;
    if (idx >= NN * H) return;
    int n = idx >> 5, o = idx & 31;
    int g = batch[n];
    atomicAdd(&gsum[g * H + o], h[idx]);
    if (o == 0) atomicAdd(&cnt[g], 1.f);
}

// ---------------- head: gx -> lin2 -> relu -> lin3 ----------------
__global__ void k_head(const float* __restrict__ gsum, const float* __restrict__ cnt,
                       const float* __restrict__ W2, const float* __restrict__ b2,
                       const float* __restrict__ W3, const float* __restrict__ b3,
                       float* __restrict__ out) {
    __shared__ float sW2[H * 16];
    __shared__ float sW3[16];
    __shared__ float sb2[16];
    int t = threadIdx.x;
    for (int j = t; j < H * 16; j += 256) sW2[j] = W2[j];
    if (t < 16) { sW3[t] = W3[t]; sb2[t] = b2[t]; }
    __syncthreads();
    int g = blockIdx.x * 256 + t;
    if (g >= NG) return;
    float inv = 1.0f / fmaxf(cnt[g], 1.0f);
    float gx[H];
#pragma unroll
    for (int i = 0; i < H; i++) gx[i] = gsum[g * H + i] * inv;
    float o3 = b3[0];
#pragma unroll
    for (int j = 0; j < 16; j++) {
        float hh = sb2[j];
#pragma unroll
        for (int i = 0; i < H; i++) hh += gx[i] * sW2[i * 16 + j];
        hh = hh > 0.f ? hh : 0.f;
        o3 += hh * sW3[j];
    }
    out[g] = o3;
}

extern "C" void kernel_launch(void* const* d_in, const int* in_sizes, int n_in,
                              void* d_out, int out_size, void* d_ws, size_t ws_size,
                              hipStream_t stream) {
    const float* x      = (const float*)d_in[0];
    const float* eattr  = (const float*)d_in[1];
    const float* W_node = (const float*)d_in[2];
    const float* b_node = (const float*)d_in[3];
    const float* W_edge = (const float*)d_in[4];
    const float* b_edge = (const float*)d_in[5];
    const float* W_nn   = (const float*)d_in[6];
    const float* b_nn   = (const float*)d_in[7];
    const float* W_root = (const float*)d_in[8];
    const float* b_conv = (const float*)d_in[9];
    const float* gamma  = (const float*)d_in[10];
    const float* beta   = (const float*)d_in[11];
    const float* W2     = (const float*)d_in[12];
    const float* b2     = (const float*)d_in[13];
    const float* W3     = (const float*)d_in[14];
    const float* b3     = (const float*)d_in[15];
    const int* eidx     = (const int*)d_in[16];
    const int* batch    = (const int*)d_in[17];
    const int* src = eidx;
    const int* dst = eidx + NE;
    float* out = (float*)d_out;

    float* ws = (float*)d_ws;
    float* h    = ws;                       // NN*32
    float* z    = h + (size_t)NN * H;       // NN*32
    float* u    = z + (size_t)NN * H;       // NN*32
    float* agg  = u + (size_t)NN * H;       // NN*32
    float* ea   = agg + (size_t)NN * H;     // NE*32
    float* Wt   = ea + (size_t)NE * FE2;    // 3*8*32*128
    float* stats = Wt + (size_t)NL * 8 * 32 * 128;  // 64
    float* gsum = stats + 64;               // NG*32
    float* cnt  = gsum + (size_t)NG * H;    // NG
    float* T    = cnt + NG;                 // NN*1024

    // prep repacked W_nn
    k_prep_wt<<<(NL * 8 * 32 * 128 + 255) / 256, 256, 0, stream>>>(W_nn, Wt);
    // embeddings
    k_node_emb<<<(NN + 7) / 8, 256, 0, stream>>>(x, W_node, b_node, h);
    k_edge_emb<<<(NE + 7) / 8, 256, 0, stream>>>(eattr, W_edge, b_edge, ea);

    for (int l = 0; l < NL; l++) {
        k_gemm_T<<<(NN + 63) / 64, 512, 0, stream>>>(h, Wt + (size_t)l * 8 * 32 * 128, T);
        k_node_lin<<<(NN + 7) / 8, 256, 0, stream>>>(h, W_root + l * H * H, b_conv + l * H,
                                                     b_nn + l * H * H, z, u);
        hipMemsetAsync(agg, 0, (size_t)NN * H * sizeof(float), stream);
        hipMemsetAsync(stats, 0, 64 * sizeof(float), stream);
        k_edge_msg<<<(NE + 7) / 8, 256, 0, stream>>>(ea, T, u, src, dst, agg);
        k_add_stats<<<512, 256, 0, stream>>>(z, agg, stats);
        k_bn_apply<<<(NN * H + 255) / 256, 256, 0, stream>>>(z, stats, gamma + l * H,
                                                             beta + l * H, h);
    }

    hipMemsetAsync(gsum, 0, (size_t)NG * H * sizeof(float), stream);
    hipMemsetAsync(cnt, 0, NG * sizeof(float), stream);
    k_pool<<<(NN * H + 255) / 256, 256, 0, stream>>>(h, batch, gsum, cnt);
    k_head<<<(NG + 255) / 256, 256, 0, stream>>>(gsum, cnt, W2, b2, W3, b3, out);
}

// Round 4
// 811.436 us; speedup vs baseline: 6.6910x; 6.6910x over previous
//
#include <hip/hip_runtime.h>

#define NN 50000
#define NE 200000
#define NG 512
#define FN 64
#define FE 16
#define FE2 32
#define H 32
#define NL 3
#define EPSV 1e-5f

// ---------------- prep: repack W_nn[l][kf][i*32+o] -> Wt2[l][cb][i][c'] ----------------
// column c = cb*128 + c' flattens (kf,o): kf = c>>5, o = c&31. Stage s = cb pair = 32 KB.
__global__ void k_prep_wt(const float* __restrict__ Wnn, float* __restrict__ Wt2) {
    int idx = blockIdx.x * 256 + threadIdx.x;
    if (idx >= NL * 8 * 32 * 128) return;
    int cp = idx & 127;
    int i  = (idx >> 7) & 31;
    int cb = (idx >> 12) & 7;
    int l  = idx >> 15;
    int c  = cb * 128 + cp;
    int kf = c >> 5, o = c & 31;
    Wt2[idx] = Wnn[((size_t)l * 32 + kf) * 1024 + i * 32 + o];
}

// ---------------- node embedding: h = x @ W_node + b_node ----------------
__global__ void k_node_emb(const float* __restrict__ x, const float* __restrict__ W,
                           const float* __restrict__ b, float* __restrict__ h) {
    __shared__ float sW[FN * H];
    int t = threadIdx.x;
    for (int j = t; j < FN * H; j += 256) sW[j] = W[j];
    __syncthreads();
    int node = blockIdx.x * 8 + (t >> 5);
    int o = t & 31;
    if (node >= NN) return;
    const float* xr = x + node * FN;
    float acc = b[o];
#pragma unroll 16
    for (int i = 0; i < FN; i++) acc += xr[i] * sW[i * H + o];
    h[node * H + o] = acc;
}

// ---------------- edge embedding: ea = edge_attr @ W_edge + b_edge ----------------
__global__ void k_edge_emb(const float* __restrict__ eattr, const float* __restrict__ W,
                           const float* __restrict__ b, float* __restrict__ ea) {
    __shared__ float sW[FE * FE2];
    int t = threadIdx.x;
    for (int j = t; j < FE * FE2; j += 256) sW[j] = W[j];
    __syncthreads();
    int e = blockIdx.x * 8 + (t >> 5);
    int o = t & 31;
    if (e >= NE) return;
    const float* er = eattr + e * FE;
    float acc = b[o];
#pragma unroll
    for (int i = 0; i < FE; i++) acc += er[i] * sW[i * FE2 + o];
    ea[e * FE2 + o] = acc;
}

// ---------------- CSR build ----------------
__global__ void k_deg(const int* __restrict__ src, int* __restrict__ deg) {
    int e = blockIdx.x * 256 + threadIdx.x;
    if (e < NE) atomicAdd(&deg[src[e]], 1);
}

__global__ void k_scan1(const int* __restrict__ deg, int* __restrict__ rowptr,
                        int* __restrict__ bsum) {
    __shared__ int s[1024];
    int t = threadIdx.x, blk = blockIdx.x;
    int idx = blk * 1024 + t;
    s[t] = (idx < NN) ? deg[idx] : 0;
    for (int off = 1; off < 1024; off <<= 1) {
        __syncthreads();
        int tv = (t >= off) ? s[t - off] : 0;
        __syncthreads();
        s[t] += tv;
    }
    __syncthreads();
    if (idx < NN) rowptr[idx + 1] = s[t];
    if (t == 1023) bsum[blk] = s[1023];
}

__global__ void k_scan2(const int* __restrict__ bsum, int* __restrict__ boff,
                        int* __restrict__ rowptr) {
    __shared__ int s[64];
    int t = threadIdx.x;
    s[t] = (t < 49) ? bsum[t] : 0;
    for (int off = 1; off < 64; off <<= 1) {
        __syncthreads();
        int tv = (t >= off) ? s[t - off] : 0;
        __syncthreads();
        s[t] += tv;
    }
    __syncthreads();
    if (t < 49) boff[t] = (t == 0) ? 0 : s[t - 1];
    if (t == 0) rowptr[0] = 0;
}

__global__ void k_scan3(int* __restrict__ rowptr, const int* __restrict__ boff) {
    int t = threadIdx.x, blk = blockIdx.x;
    int idx = blk * 1024 + t;
    if (idx < NN) rowptr[idx + 1] += boff[blk];
}

__global__ void k_cursor(const int* __restrict__ rowptr, int* __restrict__ cursor) {
    int i = blockIdx.x * 256 + threadIdx.x;
    if (i < NN) cursor[i] = rowptr[i];
}

__global__ void k_fill(const int* __restrict__ src, int* __restrict__ cursor,
                       int* __restrict__ eid) {
    int e = blockIdx.x * 256 + threadIdx.x;
    if (e >= NE) return;
    int p = atomicAdd(&cursor[src[e]], 1);
    eid[p] = e;
}

// ---------------- node linear: z = h@W_root + b_conv ; u = h@Bnn ----------------
__global__ void k_node_lin(const float* __restrict__ h, const float* __restrict__ Wr,
                           const float* __restrict__ bc, const float* __restrict__ bnn,
                           float* __restrict__ z, float* __restrict__ u) {
    __shared__ float sWr[H * H];
    __shared__ float sBn[H * H];
    int t = threadIdx.x;
    for (int j = t; j < H * H; j += 256) { sWr[j] = Wr[j]; sBn[j] = bnn[j]; }
    __syncthreads();
    int node = blockIdx.x * 8 + (t >> 5);
    int o = t & 31;
    if (node >= NN) return;
    const float* hr = h + node * H;
    float a = bc[o], bacc = 0.f;
#pragma unroll
    for (int i = 0; i < H; i++) {
        float hv = hr[i];
        a += hv * sWr[i * H + o];
        bacc += hv * sBn[i * H + o];
    }
    z[node * H + o] = a;
    u[node * H + o] = bacc;
}

// ---------------- fused NNConv: per-block T-tile in LDS + edge apply ----------------
// Block owns 8 contiguous nodes. Phase A: T[8][1024] = h_tile @ Wt (4 staged 32KB
// weight slices, L2-hot). Phase B: for the block's contiguous CSR edge bucket,
// m = u_src + ea_e . T_src (T read from LDS), atomicAdd into agg[dst].
__global__ __launch_bounds__(256, 2) void k_conv(
    const float* __restrict__ h, const float* __restrict__ u,
    const float* __restrict__ ea, const float* __restrict__ Wt2l,
    const int* __restrict__ rowptr, const int* __restrict__ eid,
    const int* __restrict__ src, const int* __restrict__ dst,
    float* __restrict__ agg) {
    __shared__ float4 sW[2048];          // 32 KB weight stage: [cbl][i][cp4]
    __shared__ float st[8][1024];        // 32 KB T tile
    __shared__ float shh[8][32];
    __shared__ float su[8][32];
    int t = threadIdx.x;
    int nb0 = blockIdx.x * 8;

    if (t < 64) {
        int n = t >> 3, qq = t & 7;
        *(float4*)&shh[n][qq * 4] = *(const float4*)(h + (size_t)(nb0 + n) * H + qq * 4);
        *(float4*)&su[n][qq * 4] = *(const float4*)(u + (size_t)(nb0 + n) * H + qq * 4);
    }

    int q = t & 63;        // column quad within 256-col stage
    int th = t >> 6;       // 0..3 -> nodes th*2, th*2+1
    int n0 = th * 2, n1 = n0 + 1;
    int wq = (q >> 5) * 1024 + (q & 31); // base float4 index for this quad

    for (int s = 0; s < 4; s++) {
        __syncthreads();   // sW readers of previous stage done (and shh/su ready at s=0)
        const float4* wsrc = (const float4*)(Wt2l + (size_t)s * 8192);
        for (int j = t; j < 2048; j += 256) sW[j] = wsrc[j];
        __syncthreads();

        float4 a0 = make_float4(0.f, 0.f, 0.f, 0.f);
        float4 a1 = a0;
#pragma unroll
        for (int i = 0; i < 32; i++) {
            float4 w = sW[wq + i * 32];
            float h0 = shh[n0][i], h1 = shh[n1][i];
            a0.x += h0 * w.x; a0.y += h0 * w.y; a0.z += h0 * w.z; a0.w += h0 * w.w;
            a1.x += h1 * w.x; a1.y += h1 * w.y; a1.z += h1 * w.z; a1.w += h1 * w.w;
        }
        int col = s * 256 + q * 4;
        *(float4*)&st[n0][col] = a0;
        *(float4*)&st[n1][col] = a1;
    }
    __syncthreads();       // T tile complete

    int E0 = rowptr[nb0], E1 = rowptr[nb0 + 8];
    int hw = t >> 5, o = t & 31;
    for (int j = E0 + hw; j < E1; j += 8) {
        int e = eid[j];
        int sn = src[e], d = dst[e];
        int ln = sn - nb0;
        float eav = ea[(size_t)e * FE2 + o];
        float m = su[ln][o];
        const float* tp = &st[ln][0];
#pragma unroll
        for (int k = 0; k < 32; k++) {
            float ek = __shfl(eav, k, 32);
            m += ek * tp[k * 32 + o];
        }
        atomicAdd(&agg[(size_t)d * H + o], m);
    }
}

// ---------------- z += agg ; accumulate per-channel sum & sumsq ----------------
__global__ void k_add_stats(float* __restrict__ z, const float* __restrict__ agg,
                            float* __restrict__ stats) {
    __shared__ float red[256];
    int t = threadIdx.x;
    float s = 0.f, s2 = 0.f;
    for (size_t idx = (size_t)blockIdx.x * 256 + t; idx < (size_t)NN * H;
         idx += (size_t)gridDim.x * 256) {
        float v = z[idx] + agg[idx];
        z[idx] = v;
        s += v;
        s2 += v * v;
    }
    red[t] = s;
    __syncthreads();
    for (int st = 128; st >= 32; st >>= 1) {
        if (t < st) red[t] += red[t + st];
        __syncthreads();
    }
    if (t < 32) atomicAdd(&stats[t], red[t]);
    __syncthreads();
    red[t] = s2;
    __syncthreads();
    for (int st = 128; st >= 32; st >>= 1) {
        if (t < st) red[t] += red[t + st];
        __syncthreads();
    }
    if (t < 32) atomicAdd(&stats[32 + t], red[t]);
}

// ---------------- BN apply + ReLU ----------------
__global__ void k_bn_apply(const float* __restrict__ z, const float* __restrict__ stats,
                           const float* __restrict__ gamma, const float* __restrict__ beta,
                           float* __restrict__ h) {
    int idx = blockIdx.x * 256 + threadIdx.x;
    if (idx >= NN * H) return;
    int o = idx & 31;
    const float invn = 1.0f / (float)NN;
    float mu = stats[o] * invn;
    float var = stats[32 + o] * invn - mu * mu;
    float v = (z[idx] - mu) * rsqrtf(var + EPSV) * gamma[o] + beta[o];
    h[idx] = v > 0.f ? v : 0.f;
}

// ---------------- pool: segment sums over graphs ----------------
__global__ void k_pool(const float* __restrict__ h, const int* __restrict__ batch,
                       float* __restrict__ gsum, float* __restrict__ cnt) {
    int idx = blockIdx.x * 256 + threadIdx.x;
    if (idx >= NN * H) return;
    int n = idx >> 5, o = idx & 31;
    int g = batch[n];
    atomicAdd(&gsum[g * H + o], h[idx]);
    if (o == 0) atomicAdd(&cnt[g], 1.f);
}

// ---------------- head: gx -> lin2 -> relu -> lin3 ----------------
__global__ void k_head(const float* __restrict__ gsum, const float* __restrict__ cnt,
                       const float* __restrict__ W2, const float* __restrict__ b2,
                       const float* __restrict__ W3, const float* __restrict__ b3,
                       float* __restrict__ out) {
    __shared__ float sW2[H * 16];
    __shared__ float sW3[16];
    __shared__ float sb2[16];
    int t = threadIdx.x;
    for (int j = t; j < H * 16; j += 256) sW2[j] = W2[j];
    if (t < 16) { sW3[t] = W3[t]; sb2[t] = b2[t]; }
    __syncthreads();
    int g = blockIdx.x * 256 + t;
    if (g >= NG) return;
    float inv = 1.0f / fmaxf(cnt[g], 1.0f);
    float gx[H];
#pragma unroll
    for (int i = 0; i < H; i++) gx[i] = gsum[g * H + i] * inv;
    float o3 = b3[0];
#pragma unroll
    for (int j = 0; j < 16; j++) {
        float hh = sb2[j];
#pragma unroll
        for (int i = 0; i < H; i++) hh += gx[i] * sW2[i * 16 + j];
        hh = hh > 0.f ? hh : 0.f;
        o3 += hh * sW3[j];
    }
    out[g] = o3;
}

extern "C" void kernel_launch(void* const* d_in, const int* in_sizes, int n_in,
                              void* d_out, int out_size, void* d_ws, size_t ws_size,
                              hipStream_t stream) {
    const float* x      = (const float*)d_in[0];
    const float* eattr  = (const float*)d_in[1];
    const float* W_node = (const float*)d_in[2];
    const float* b_node = (const float*)d_in[3];
    const float* W_edge = (const float*)d_in[4];
    const float* b_edge = (const float*)d_in[5];
    const float* W_nn   = (const float*)d_in[6];
    const float* b_nn   = (const float*)d_in[7];
    const float* W_root = (const float*)d_in[8];
    const float* b_conv = (const float*)d_in[9];
    const float* gamma  = (const float*)d_in[10];
    const float* beta   = (const float*)d_in[11];
    const float* W2     = (const float*)d_in[12];
    const float* b2     = (const float*)d_in[13];
    const float* W3     = (const float*)d_in[14];
    const float* b3     = (const float*)d_in[15];
    const int* eidx     = (const int*)d_in[16];
    const int* batch    = (const int*)d_in[17];
    const int* src = eidx;
    const int* dst = eidx + NE;
    float* out = (float*)d_out;

    float* ws = (float*)d_ws;
    float* h    = ws;                        // NN*32
    float* z    = h + (size_t)NN * H;        // NN*32
    float* u    = z + (size_t)NN * H;        // NN*32
    float* agg  = u + (size_t)NN * H;        // NN*32
    float* ea   = agg + (size_t)NN * H;      // NE*32
    float* Wt   = ea + (size_t)NE * FE2;     // 3*8*32*128 = 98304
    float* stats = Wt + (size_t)NL * 8 * 32 * 128;  // 64
    float* gsum = stats + 64;                // NG*32
    float* cnt  = gsum + (size_t)NG * H;     // NG
    int* ip     = (int*)(cnt + NG);
    int* deg    = ip;                        // NN
    int* rowptr = deg + NN;                  // NN+1
    int* cursor = rowptr + NN + 1;           // NN
    int* eid    = cursor + NN;               // NE
    int* bsum   = eid + NE;                  // 64
    int* boff   = bsum + 64;                 // 64

    // one-time prep
    k_prep_wt<<<(NL * 8 * 32 * 128 + 255) / 256, 256, 0, stream>>>(W_nn, Wt);
    k_node_emb<<<(NN + 7) / 8, 256, 0, stream>>>(x, W_node, b_node, h);
    k_edge_emb<<<(NE + 7) / 8, 256, 0, stream>>>(eattr, W_edge, b_edge, ea);

    // CSR by src
    hipMemsetAsync(deg, 0, NN * sizeof(int), stream);
    k_deg<<<(NE + 255) / 256, 256, 0, stream>>>(src, deg);
    k_scan1<<<49, 1024, 0, stream>>>(deg, rowptr, bsum);
    k_scan2<<<1, 64, 0, stream>>>(bsum, boff, rowptr);
    k_scan3<<<49, 1024, 0, stream>>>(rowptr, boff);
    k_cursor<<<(NN + 255) / 256, 256, 0, stream>>>(rowptr, cursor);
    k_fill<<<(NE + 255) / 256, 256, 0, stream>>>(src, cursor, eid);

    for (int l = 0; l < NL; l++) {
        k_node_lin<<<(NN + 7) / 8, 256, 0, stream>>>(h, W_root + l * H * H, b_conv + l * H,
                                                     b_nn + l * H * H, z, u);
        hipMemsetAsync(agg, 0, (size_t)NN * H * sizeof(float), stream);
        hipMemsetAsync(stats, 0, 64 * sizeof(float), stream);
        k_conv<<<NN / 8, 256, 0, stream>>>(h, u, ea, Wt + (size_t)l * 8 * 32 * 128,
                                           rowptr, eid, src, dst, agg);
        k_add_stats<<<512, 256, 0, stream>>>(z, agg, stats);
        k_bn_apply<<<(NN * H + 255) / 256, 256, 0, stream>>>(z, stats, gamma + l * H,
                                                             beta + l * H, h);
    }

    hipMemsetAsync(gsum, 0, (size_t)NG * H * sizeof(float), stream);
    hipMemsetAsync(cnt, 0, NG * sizeof(float), stream);
    k_pool<<<(NN * H + 255) / 256, 256, 0, stream>>>(h, batch, gsum, cnt);
    k_head<<<(NG + 255) / 256, 256, 0, stream>>>(gsum, cnt, W2, b2, W3, b3, out);
}

// Round 5
// 715.552 us; speedup vs baseline: 7.5876x; 1.1340x over previous
//
#include <hip/hip_runtime.h>

#define NN 50000
#define NE 200000
#define NG 512
#define FN 64
#define FE 16
#define FE2 32
#define H 32
#define NL 3
#define EPSV 1e-5f

// ---------------- prep: repack W_nn into staged tiles ----------------
// WtX[l][hf][ch][ih][ip][cp]: i = ih*16+ip, col c = hf*512+ch*256+cp, (kf,o)=(c>>5,c&31)
// Each [ih][ip][cp] tile is 16x256 floats = 16 KB, contiguous.
__global__ void k_prep_wt(const float* __restrict__ Wnn, float* __restrict__ WtX) {
    int idx = blockIdx.x * 256 + threadIdx.x;
    if (idx >= NL * 32768) return;
    int cp = idx & 255;
    int ip = (idx >> 8) & 15;
    int ih = (idx >> 12) & 1;
    int ch = (idx >> 13) & 1;
    int hf = (idx >> 14) & 1;
    int l  = idx >> 15;
    int i = ih * 16 + ip;
    int c = hf * 512 + ch * 256 + cp;
    int kf = c >> 5, o = c & 31;
    WtX[idx] = Wnn[((size_t)l * 32 + kf) * 1024 + i * 32 + o];
}

// ---------------- node embedding: h = x @ W_node + b_node ----------------
__global__ void k_node_emb(const float* __restrict__ x, const float* __restrict__ W,
                           const float* __restrict__ b, float* __restrict__ h) {
    __shared__ float sW[FN * H];
    int t = threadIdx.x;
    for (int j = t; j < FN * H; j += 256) sW[j] = W[j];
    __syncthreads();
    int node = blockIdx.x * 8 + (t >> 5);
    int o = t & 31;
    if (node >= NN) return;
    const float* xr = x + node * FN;
    float acc = b[o];
#pragma unroll 16
    for (int i = 0; i < FN; i++) acc += xr[i] * sW[i * H + o];
    h[node * H + o] = acc;
}

// ---------------- edge embedding: ea = edge_attr @ W_edge + b_edge ----------------
__global__ void k_edge_emb(const float* __restrict__ eattr, const float* __restrict__ W,
                           const float* __restrict__ b, float* __restrict__ ea) {
    __shared__ float sW[FE * FE2];
    int t = threadIdx.x;
    for (int j = t; j < FE * FE2; j += 256) sW[j] = W[j];
    __syncthreads();
    int e = blockIdx.x * 8 + (t >> 5);
    int o = t & 31;
    if (e >= NE) return;
    const float* er = eattr + e * FE;
    float acc = b[o];
#pragma unroll
    for (int i = 0; i < FE; i++) acc += er[i] * sW[i * FE2 + o];
    ea[e * FE2 + o] = acc;
}

// ---------------- CSR build ----------------
__global__ void k_deg(const int* __restrict__ src, int* __restrict__ deg) {
    int e = blockIdx.x * 256 + threadIdx.x;
    if (e < NE) atomicAdd(&deg[src[e]], 1);
}

__global__ void k_scan1(const int* __restrict__ deg, int* __restrict__ rowptr,
                        int* __restrict__ bsum) {
    __shared__ int s[1024];
    int t = threadIdx.x, blk = blockIdx.x;
    int idx = blk * 1024 + t;
    s[t] = (idx < NN) ? deg[idx] : 0;
    for (int off = 1; off < 1024; off <<= 1) {
        __syncthreads();
        int tv = (t >= off) ? s[t - off] : 0;
        __syncthreads();
        s[t] += tv;
    }
    __syncthreads();
    if (idx < NN) rowptr[idx + 1] = s[t];
    if (t == 1023) bsum[blk] = s[1023];
}

__global__ void k_scan2(const int* __restrict__ bsum, int* __restrict__ boff,
                        int* __restrict__ rowptr) {
    __shared__ int s[64];
    int t = threadIdx.x;
    s[t] = (t < 49) ? bsum[t] : 0;
    for (int off = 1; off < 64; off <<= 1) {
        __syncthreads();
        int tv = (t >= off) ? s[t - off] : 0;
        __syncthreads();
        s[t] += tv;
    }
    __syncthreads();
    if (t < 49) boff[t] = (t == 0) ? 0 : s[t - 1];
    if (t == 0) rowptr[0] = 0;
}

__global__ void k_scan3(int* __restrict__ rowptr, const int* __restrict__ boff) {
    int t = threadIdx.x, blk = blockIdx.x;
    int idx = blk * 1024 + t;
    if (idx < NN) rowptr[idx + 1] += boff[blk];
}

__global__ void k_cursor(const int* __restrict__ rowptr, int* __restrict__ cursor) {
    int i = blockIdx.x * 256 + threadIdx.x;
    if (i < NN) cursor[i] = rowptr[i];
}

__global__ void k_fill(const int* __restrict__ src, int* __restrict__ cursor,
                       int* __restrict__ eid) {
    int e = blockIdx.x * 256 + threadIdx.x;
    if (e >= NE) return;
    int p = atomicAdd(&cursor[src[e]], 1);
    eid[p] = e;
}

// ---------------- cnt: graph-size histogram (layer-independent) ----------------
__global__ void k_cnt(const int* __restrict__ batch, float* __restrict__ cnt) {
    int i = blockIdx.x * 256 + threadIdx.x;
    if (i < NN) atomicAdd(&cnt[batch[i]], 1.f);
}

// ---------------- node linear (layer 0 only): z = h@W_root + b_conv ; u = h@Bnn ----------------
__global__ void k_node_lin(const float* __restrict__ h, const float* __restrict__ Wr,
                           const float* __restrict__ bc, const float* __restrict__ bnn,
                           float* __restrict__ z, float* __restrict__ u) {
    __shared__ float sWr[H * H];
    __shared__ float sBn[H * H];
    int t = threadIdx.x;
    for (int j = t; j < H * H; j += 256) { sWr[j] = Wr[j]; sBn[j] = bnn[j]; }
    __syncthreads();
    int node = blockIdx.x * 8 + (t >> 5);
    int o = t & 31;
    if (node >= NN) return;
    const float* hr = h + node * H;
    float a = bc[o], bacc = 0.f;
#pragma unroll
    for (int i = 0; i < H; i++) {
        float hv = hr[i];
        a += hv * sWr[i * H + o];
        bacc += hv * sBn[i * H + o];
    }
    z[node * H + o] = a;
    u[node * H + o] = bacc;
}

// ---------------- fused NNConv, k-split: half T-tile in LDS + edge apply x2 ----------------
// Block owns 8 contiguous nodes. Per k-half: T[8][512] built from 4 staged 16 KB
// weight tiles; then the block's CSR edge bucket applies this half:
// m_half = (half==0 ? u_src : 0) + sum_{k in half} ea_e[k] * T[src][k*32+o],
// atomicAdd into agg[dst]. LDS ~34.5 KB -> 4 blocks/CU.
__global__ __launch_bounds__(256, 4) void k_conv(
    const float* __restrict__ h, const float* __restrict__ u,
    const float* __restrict__ ea, const float* __restrict__ WtXl,
    const int* __restrict__ rowptr, const int* __restrict__ eid,
    const int* __restrict__ src, const int* __restrict__ dst,
    float* __restrict__ agg) {
    __shared__ float4 sW4[1024];         // 16 KB weight tile [ip][cp4]
    __shared__ float st[8][512];         // 16 KB half T tile
    __shared__ float shh[8][32];
    __shared__ float su[8][32];
    int t = threadIdx.x;
    int nb0 = blockIdx.x * 8;

    if (t < 64) {
        int n = t >> 3, qq = t & 7;
        *(float4*)&shh[n][qq * 4] = *(const float4*)(h + (size_t)(nb0 + n) * H + qq * 4);
        *(float4*)&su[n][qq * 4] = *(const float4*)(u + (size_t)(nb0 + n) * H + qq * 4);
    }

    int q = t & 63;                      // float4-col within 256-col group
    int th = t >> 6;                     // 0..3 -> nodes 2th, 2th+1
    int n0 = th * 2, n1 = n0 + 1;
    int hw = t >> 5, o = t & 31;
    int E0 = rowptr[nb0], E1 = rowptr[nb0 + 8];

    for (int hf = 0; hf < 2; hf++) {
        for (int ch = 0; ch < 2; ch++) {
            float4 a0 = make_float4(0.f, 0.f, 0.f, 0.f);
            float4 a1 = a0;
            for (int ih = 0; ih < 2; ih++) {
                __syncthreads();         // sW/st readers of previous phase done
                const float4* wsrc =
                    (const float4*)(WtXl + (size_t)(((hf * 2 + ch) * 2 + ih) * 4096));
                for (int j = t; j < 1024; j += 256) sW4[j] = wsrc[j];
                __syncthreads();
#pragma unroll
                for (int ip4 = 0; ip4 < 4; ip4++) {
                    float4 h0 = *(const float4*)&shh[n0][ih * 16 + ip4 * 4];
                    float4 h1 = *(const float4*)&shh[n1][ih * 16 + ip4 * 4];
#pragma unroll
                    for (int r = 0; r < 4; r++) {
                        float4 w = sW4[(ip4 * 4 + r) * 64 + q];
                        float v0 = (r == 0) ? h0.x : (r == 1) ? h0.y : (r == 2) ? h0.z : h0.w;
                        float v1 = (r == 0) ? h1.x : (r == 1) ? h1.y : (r == 2) ? h1.z : h1.w;
                        a0.x += v0 * w.x; a0.y += v0 * w.y; a0.z += v0 * w.z; a0.w += v0 * w.w;
                        a1.x += v1 * w.x; a1.y += v1 * w.y; a1.z += v1 * w.z; a1.w += v1 * w.w;
                    }
                }
            }
            *(float4*)&st[n0][ch * 256 + q * 4] = a0;
            *(float4*)&st[n1][ch * 256 + q * 4] = a1;
        }
        __syncthreads();                 // half T tile complete

        int base = hf * 16;
        for (int j = E0 + hw; j < E1; j += 8) {
            int e = eid[j];
            int sn = src[e], d = dst[e];
            int ln = sn - nb0;
            float eav = ea[(size_t)e * FE2 + o];
            float m = (hf == 0) ? su[ln][o] : 0.f;
            const float* tp = &st[ln][0];
#pragma unroll
            for (int k2 = 0; k2 < 16; k2++) {
                float ek = __shfl(eav, base + k2, 32);
                m += ek * tp[k2 * 32 + o];
            }
            atomicAdd(&agg[(size_t)d * H + o], m);
        }
    }
}

// ---------------- z += agg ; accumulate per-channel sum & sumsq ----------------
__global__ void k_add_stats(float* __restrict__ z, const float* __restrict__ agg,
                            float* __restrict__ stats) {
    __shared__ float red[256];
    int t = threadIdx.x;
    float s = 0.f, s2 = 0.f;
    for (size_t idx = (size_t)blockIdx.x * 256 + t; idx < (size_t)NN * H;
         idx += (size_t)gridDim.x * 256) {
        float v = z[idx] + agg[idx];
        z[idx] = v;
        s += v;
        s2 += v * v;
    }
    red[t] = s;
    __syncthreads();
    for (int st = 128; st >= 32; st >>= 1) {
        if (t < st) red[t] += red[t + st];
        __syncthreads();
    }
    if (t < 32) atomicAdd(&stats[t], red[t]);
    __syncthreads();
    red[t] = s2;
    __syncthreads();
    for (int st = 128; st >= 32; st >>= 1) {
        if (t < st) red[t] += red[t + st];
        __syncthreads();
    }
    if (t < 32) atomicAdd(&stats[32 + t], red[t]);
}

// ---------------- fused BN+ReLU -> next layer's node linear ----------------
__global__ void k_bn_lin(const float* __restrict__ z, const float* __restrict__ stats,
                         const float* __restrict__ gm, const float* __restrict__ bt,
                         const float* __restrict__ Wr, const float* __restrict__ bc,
                         const float* __restrict__ bnn, float* __restrict__ hout,
                         float* __restrict__ zout, float* __restrict__ uout) {
    __shared__ float sWr[H * H];
    __shared__ float sBn[H * H];
    __shared__ float sh[8][32];
    int t = threadIdx.x;
    for (int j = t; j < H * H; j += 256) { sWr[j] = Wr[j]; sBn[j] = bnn[j]; }
    int node = t >> 5, o = t & 31;
    size_t idx = (size_t)(blockIdx.x * 8 + node) * H + o;
    const float invn = 1.0f / (float)NN;
    float mu = stats[o] * invn;
    float var = stats[32 + o] * invn - mu * mu;
    float v = (z[idx] - mu) * rsqrtf(var + EPSV) * gm[o] + bt[o];
    v = v > 0.f ? v : 0.f;
    sh[node][o] = v;
    hout[idx] = v;
    __syncthreads();
    float a = bc[o], bacc = 0.f;
#pragma unroll
    for (int i = 0; i < H; i++) {
        float hv = sh[node][i];
        a += hv * sWr[i * H + o];
        bacc += hv * sBn[i * H + o];
    }
    zout[idx] = a;
    uout[idx] = bacc;
}

// ---------------- fused BN+ReLU -> graph pool (last layer; h never stored) ----------------
__global__ void k_bn_pool(const float* __restrict__ z, const float* __restrict__ stats,
                          const float* __restrict__ gm, const float* __restrict__ bt,
                          const int* __restrict__ batch, float* __restrict__ gsum) {
    int idx = blockIdx.x * 256 + threadIdx.x;
    if (idx >= NN * H) return;
    int n = idx >> 5, o = idx & 31;
    const float invn = 1.0f / (float)NN;
    float mu = stats[o] * invn;
    float var = stats[32 + o] * invn - mu * mu;
    float v = (z[idx] - mu) * rsqrtf(var + EPSV) * gm[o] + bt[o];
    v = v > 0.f ? v : 0.f;
    atomicAdd(&gsum[(size_t)batch[n] * H + o], v);
}

// ---------------- head: gx -> lin2 -> relu -> lin3 ----------------
__global__ void k_head(const float* __restrict__ gsum, const float* __restrict__ cnt,
                       const float* __restrict__ W2, const float* __restrict__ b2,
                       const float* __restrict__ W3, const float* __restrict__ b3,
                       float* __restrict__ out) {
    __shared__ float sW2[H * 16];
    __shared__ float sW3[16];
    __shared__ float sb2[16];
    int t = threadIdx.x;
    for (int j = t; j < H * 16; j += 256) sW2[j] = W2[j];
    if (t < 16) { sW3[t] = W3[t]; sb2[t] = b2[t]; }
    __syncthreads();
    int g = blockIdx.x * 256 + t;
    if (g >= NG) return;
    float inv = 1.0f / fmaxf(cnt[g], 1.0f);
    float gx[H];
#pragma unroll
    for (int i = 0; i < H; i++) gx[i] = gsum[g * H + i] * inv;
    float o3 = b3[0];
#pragma unroll
    for (int j = 0; j < 16; j++) {
        float hh = sb2[j];
#pragma unroll
        for (int i = 0; i < H; i++) hh += gx[i] * sW2[i * 16 + j];
        hh = hh > 0.f ? hh : 0.f;
        o3 += hh * sW3[j];
    }
    out[g] = o3;
}

extern "C" void kernel_launch(void* const* d_in, const int* in_sizes, int n_in,
                              void* d_out, int out_size, void* d_ws, size_t ws_size,
                              hipStream_t stream) {
    const float* x      = (const float*)d_in[0];
    const float* eattr  = (const float*)d_in[1];
    const float* W_node = (const float*)d_in[2];
    const float* b_node = (const float*)d_in[3];
    const float* W_edge = (const float*)d_in[4];
    const float* b_edge = (const float*)d_in[5];
    const float* W_nn   = (const float*)d_in[6];
    const float* b_nn   = (const float*)d_in[7];
    const float* W_root = (const float*)d_in[8];
    const float* b_conv = (const float*)d_in[9];
    const float* gamma  = (const float*)d_in[10];
    const float* beta   = (const float*)d_in[11];
    const float* W2     = (const float*)d_in[12];
    const float* b2     = (const float*)d_in[13];
    const float* W3     = (const float*)d_in[14];
    const float* b3     = (const float*)d_in[15];
    const int* eidx     = (const int*)d_in[16];
    const int* batch    = (const int*)d_in[17];
    const int* src = eidx;
    const int* dst = eidx + NE;
    float* out = (float*)d_out;

    float* ws = (float*)d_ws;
    float* h    = ws;                        // NN*32
    float* z    = h + (size_t)NN * H;        // NN*32
    float* u    = z + (size_t)NN * H;        // NN*32
    float* agg  = u + (size_t)NN * H;        // NN*32
    float* stats = agg + (size_t)NN * H;     // 64 (adjacent to agg: single memset)
    float* ea   = stats + 64;                // NE*32
    float* Wt   = ea + (size_t)NE * FE2;     // 3*32768
    float* gsum = Wt + (size_t)NL * 32768;   // NG*32
    float* cnt  = gsum + (size_t)NG * H;     // NG
    int* ip     = (int*)(cnt + NG);
    int* deg    = ip;                        // NN
    int* rowptr = deg + NN;                  // NN+1
    int* cursor = rowptr + NN + 1;           // NN
    int* eid    = cursor + NN;               // NE
    int* bsum   = eid + NE;                  // 64
    int* boff   = bsum + 64;                 // 64

    // one-time prep
    k_prep_wt<<<(NL * 32768 + 255) / 256, 256, 0, stream>>>(W_nn, Wt);
    k_node_emb<<<(NN + 7) / 8, 256, 0, stream>>>(x, W_node, b_node, h);
    k_edge_emb<<<(NE + 7) / 8, 256, 0, stream>>>(eattr, W_edge, b_edge, ea);

    // CSR by src + graph counts + gsum zero
    hipMemsetAsync(deg, 0, NN * sizeof(int), stream);
    hipMemsetAsync(gsum, 0, ((size_t)NG * H + NG) * sizeof(float), stream);
    k_deg<<<(NE + 255) / 256, 256, 0, stream>>>(src, deg);
    k_scan1<<<49, 1024, 0, stream>>>(deg, rowptr, bsum);
    k_scan2<<<1, 64, 0, stream>>>(bsum, boff, rowptr);
    k_scan3<<<49, 1024, 0, stream>>>(rowptr, boff);
    k_cursor<<<(NN + 255) / 256, 256, 0, stream>>>(rowptr, cursor);
    k_fill<<<(NE + 255) / 256, 256, 0, stream>>>(src, cursor, eid);
    k_cnt<<<(NN + 255) / 256, 256, 0, stream>>>(batch, cnt);

    // layer 0 node-linear
    k_node_lin<<<(NN + 7) / 8, 256, 0, stream>>>(h, W_root, b_conv, b_nn, z, u);

    for (int l = 0; l < NL; l++) {
        hipMemsetAsync(agg, 0, ((size_t)NN * H + 64) * sizeof(float), stream);
        k_conv<<<NN / 8, 256, 0, stream>>>(h, u, ea, Wt + (size_t)l * 32768,
                                           rowptr, eid, src, dst, agg);
        k_add_stats<<<512, 256, 0, stream>>>(z, agg, stats);
        if (l < NL - 1) {
            k_bn_lin<<<NN / 8, 256, 0, stream>>>(z, stats, gamma + l * H, beta + l * H,
                                                 W_root + (l + 1) * H * H,
                                                 b_conv + (l + 1) * H,
                                                 b_nn + (size_t)(l + 1) * H * H,
                                                 h, z, u);
        } else {
            k_bn_pool<<<(NN * H + 255) / 256, 256, 0, stream>>>(z, stats, gamma + l * H,
                                                                beta + l * H, batch, gsum);
        }
    }

    k_head<<<(NG + 255) / 256, 256, 0, stream>>>(gsum, cnt, W2, b2, W3, b3, out);
}

// Round 6
// 508.082 us; speedup vs baseline: 10.6859x; 1.4083x over previous
//
#include <hip/hip_runtime.h>

#define NN 50000
#define NE 200000
#define NG 512
#define FN 64
#define FE 16
#define FE2 32
#define H 32
#define NL 3
#define EPSV 1e-5f

// ---------------- prep: repack W_nn[l][kf][i][o] -> Wt2[l][i][c], c = kf*32+o ----------------
// Row i of Wt2 is 1024 floats (4 KB) contiguous: perfect wave-coalesced float4 streams.
__global__ void k_prep_wt(const float* __restrict__ Wnn, float* __restrict__ Wt2) {
    int idx = blockIdx.x * 256 + threadIdx.x;
    if (idx >= NL * H * 1024) return;
    int c = idx & 1023;
    int i = (idx >> 10) & 31;
    int l = idx >> 15;
    int kf = c >> 5, o = c & 31;
    Wt2[idx] = Wnn[((size_t)(l * 32 + kf)) * 1024 + i * 32 + o];
}

// ---------------- fused node embedding + layer-0 node linear ----------------
// h = x@W_node + b_node ; z = h@W_root0 + b_conv0 ; u = h@Bnn0
__global__ void k_emb_lin(const float* __restrict__ x, const float* __restrict__ Wn,
                          const float* __restrict__ bn, const float* __restrict__ Wr,
                          const float* __restrict__ bc, const float* __restrict__ bnn,
                          float* __restrict__ h, float* __restrict__ z,
                          float* __restrict__ u) {
    __shared__ float sW[FN * H];
    __shared__ float sWr[H * H];
    __shared__ float sBn[H * H];
    __shared__ float sx[8][FN];
    __shared__ float sh[8][H];
    int t = threadIdx.x;
    for (int j = t; j < FN * H; j += 256) sW[j] = Wn[j];
    for (int j = t; j < H * H; j += 256) { sWr[j] = Wr[j]; sBn[j] = bnn[j]; }
    int nb = blockIdx.x * 8;
    if (t < 128) {
        int n = t >> 4, qq = t & 15;
        *(float4*)&sx[n][qq * 4] = *(const float4*)(x + (size_t)(nb + n) * FN + qq * 4);
    }
    __syncthreads();
    int node = t >> 5, o = t & 31;
    float acc = bn[o];
#pragma unroll 16
    for (int i = 0; i < FN; i++) acc += sx[node][i] * sW[i * H + o];
    sh[node][o] = acc;
    size_t idx = (size_t)(nb + node) * H + o;
    h[idx] = acc;
    __syncthreads();
    float a = bc[o], bacc = 0.f;
#pragma unroll
    for (int i = 0; i < H; i++) {
        float hv = sh[node][i];
        a += hv * sWr[i * H + o];
        bacc += hv * sBn[i * H + o];
    }
    z[idx] = a;
    u[idx] = bacc;
}

// ---------------- edge embedding: ea = edge_attr @ W_edge + b_edge ----------------
__global__ void k_edge_emb(const float* __restrict__ eattr, const float* __restrict__ W,
                           const float* __restrict__ b, float* __restrict__ ea) {
    __shared__ float sW[FE * FE2];
    int t = threadIdx.x;
    for (int j = t; j < FE * FE2; j += 256) sW[j] = W[j];
    __syncthreads();
    int e = blockIdx.x * 8 + (t >> 5);
    int o = t & 31;
    if (e >= NE) return;
    const float* er = eattr + e * FE;
    float acc = b[o];
#pragma unroll
    for (int i = 0; i < FE; i++) acc += er[i] * sW[i * FE2 + o];
    ea[e * FE2 + o] = acc;
}

// ---------------- CSR build (+ graph-size histogram) ----------------
__global__ void k_deg_cnt(const int* __restrict__ src, int* __restrict__ deg,
                          const int* __restrict__ batch, float* __restrict__ cnt) {
    int e = blockIdx.x * 256 + threadIdx.x;
    if (e < NE) atomicAdd(&deg[src[e]], 1);
    if (e < NN) atomicAdd(&cnt[batch[e]], 1.f);
}

__global__ void k_scan1(const int* __restrict__ deg, int* __restrict__ rowptr,
                        int* __restrict__ bsum) {
    __shared__ int s[1024];
    int t = threadIdx.x, blk = blockIdx.x;
    int idx = blk * 1024 + t;
    s[t] = (idx < NN) ? deg[idx] : 0;
    for (int off = 1; off < 1024; off <<= 1) {
        __syncthreads();
        int tv = (t >= off) ? s[t - off] : 0;
        __syncthreads();
        s[t] += tv;
    }
    __syncthreads();
    if (idx < NN) rowptr[idx + 1] = s[t];
    if (t == 1023) bsum[blk] = s[1023];
}

__global__ void k_scan2(const int* __restrict__ bsum, int* __restrict__ boff,
                        int* __restrict__ rowptr) {
    __shared__ int s[64];
    int t = threadIdx.x;
    s[t] = (t < 49) ? bsum[t] : 0;
    for (int off = 1; off < 64; off <<= 1) {
        __syncthreads();
        int tv = (t >= off) ? s[t - off] : 0;
        __syncthreads();
        s[t] += tv;
    }
    __syncthreads();
    if (t < 49) boff[t] = (t == 0) ? 0 : s[t - 1];
    if (t == 0) rowptr[0] = 0;
}

__global__ void k_scan3(int* __restrict__ rowptr, const int* __restrict__ boff,
                        int* __restrict__ cursor) {
    int t = threadIdx.x, blk = blockIdx.x;
    int idx = blk * 1024 + t;
    if (idx < NN) {
        int v = rowptr[idx + 1] + boff[blk];
        rowptr[idx + 1] = v;
        if (idx + 1 < NN) cursor[idx + 1] = v;
    }
    if (idx == 0) cursor[0] = 0;
}

__global__ void k_fill(const int* __restrict__ src, int* __restrict__ cursor,
                       int* __restrict__ eid) {
    int e = blockIdx.x * 256 + threadIdx.x;
    if (e >= NE) return;
    int p = atomicAdd(&cursor[src[e]], 1);
    eid[p] = e;
}

// ---------------- fused NNConv v3: barrier-free Phase A, weights direct from L2 ----------------
// Block owns 8 contiguous nodes. Phase A: wave w owns col-group w (256 cols);
// each thread computes acc[8 nodes] x 4 cols, streaming w-rows as coalesced 1 KB
// float4 loads from L2 (Wt2 i-major). T[8][1024] lands in LDS. Phase B: block's
// CSR edge bucket applies T: m = u_src + ea_e . T_src, atomicAdd into agg[dst].
__global__ __launch_bounds__(256, 4) void k_conv(
    const float* __restrict__ h, const float* __restrict__ u,
    const float* __restrict__ ea, const float* __restrict__ Wt2l,
    const int* __restrict__ rowptr, const int* __restrict__ eid,
    const int* __restrict__ src, const int* __restrict__ dst,
    float* __restrict__ agg) {
    __shared__ float st[8][1024];        // 32 KB T tile
    __shared__ float shh[8][32];
    __shared__ float su[8][32];
    int t = threadIdx.x;
    int nb0 = blockIdx.x * 8;

    if (t < 64) {
        int n = t >> 3, qq = t & 7;
        *(float4*)&shh[n][qq * 4] = *(const float4*)(h + (size_t)(nb0 + n) * H + qq * 4);
        *(float4*)&su[n][qq * 4] = *(const float4*)(u + (size_t)(nb0 + n) * H + qq * 4);
    }
    __syncthreads();

    int q = t & 63;                      // float4-col within the wave's 256-col group
    int cg = t >> 6;                     // wave id = col group
    float4 acc[8];
#pragma unroll
    for (int n = 0; n < 8; n++) acc[n] = make_float4(0.f, 0.f, 0.f, 0.f);
    const float4* wp = (const float4*)Wt2l + cg * 64 + q;   // wp[i*256] = row i

#pragma unroll
    for (int i4 = 0; i4 < 8; i4++) {
        float4 w0 = wp[(i4 * 4 + 0) * 256];
        float4 w1 = wp[(i4 * 4 + 1) * 256];
        float4 w2 = wp[(i4 * 4 + 2) * 256];
        float4 w3 = wp[(i4 * 4 + 3) * 256];
#pragma unroll
        for (int n = 0; n < 8; n++) {
            float4 hv = *(const float4*)&shh[n][i4 * 4];
            acc[n].x += hv.x * w0.x; acc[n].y += hv.x * w0.y;
            acc[n].z += hv.x * w0.z; acc[n].w += hv.x * w0.w;
            acc[n].x += hv.y * w1.x; acc[n].y += hv.y * w1.y;
            acc[n].z += hv.y * w1.z; acc[n].w += hv.y * w1.w;
            acc[n].x += hv.z * w2.x; acc[n].y += hv.z * w2.y;
            acc[n].z += hv.z * w2.z; acc[n].w += hv.z * w2.w;
            acc[n].x += hv.w * w3.x; acc[n].y += hv.w * w3.y;
            acc[n].z += hv.w * w3.z; acc[n].w += hv.w * w3.w;
        }
    }
#pragma unroll
    for (int n = 0; n < 8; n++)
        *(float4*)&st[n][cg * 256 + q * 4] = acc[n];
    __syncthreads();                     // T tile complete

    int E0 = rowptr[nb0], E1 = rowptr[nb0 + 8];
    int hw = t >> 5, o = t & 31;
    for (int j = E0 + hw; j < E1; j += 8) {
        int e = eid[j];
        int sn = src[e], d = dst[e];
        int ln = sn - nb0;
        float eav = ea[(size_t)e * FE2 + o];
        float m = su[ln][o];
        const float* tp = &st[ln][0];
#pragma unroll
        for (int k = 0; k < 32; k++) {
            float ek = __shfl(eav, k, 32);
            m += ek * tp[k * 32 + o];
        }
        atomicAdd(&agg[(size_t)d * H + o], m);
    }
}

// ---------------- z += agg ; accumulate per-channel sum & sumsq ----------------
__global__ void k_add_stats(float* __restrict__ z, const float* __restrict__ agg,
                            float* __restrict__ stats) {
    __shared__ float red[256];
    int t = threadIdx.x;
    float s = 0.f, s2 = 0.f;
    for (size_t idx = (size_t)blockIdx.x * 256 + t; idx < (size_t)NN * H;
         idx += (size_t)gridDim.x * 256) {
        float v = z[idx] + agg[idx];
        z[idx] = v;
        s += v;
        s2 += v * v;
    }
    red[t] = s;
    __syncthreads();
    for (int st = 128; st >= 32; st >>= 1) {
        if (t < st) red[t] += red[t + st];
        __syncthreads();
    }
    if (t < 32) atomicAdd(&stats[t], red[t]);
    __syncthreads();
    red[t] = s2;
    __syncthreads();
    for (int st = 128; st >= 32; st >>= 1) {
        if (t < st) red[t] += red[t + st];
        __syncthreads();
    }
    if (t < 32) atomicAdd(&stats[32 + t], red[t]);
}

// ---------------- fused BN+ReLU -> next layer's node linear ----------------
__global__ void k_bn_lin(const float* __restrict__ z, const float* __restrict__ stats,
                         const float* __restrict__ gm, const float* __restrict__ bt,
                         const float* __restrict__ Wr, const float* __restrict__ bc,
                         const float* __restrict__ bnn, float* __restrict__ hout,
                         float* __restrict__ zout, float* __restrict__ uout) {
    __shared__ float sWr[H * H];
    __shared__ float sBn[H * H];
    __shared__ float sh[8][32];
    int t = threadIdx.x;
    for (int j = t; j < H * H; j += 256) { sWr[j] = Wr[j]; sBn[j] = bnn[j]; }
    int node = t >> 5, o = t & 31;
    size_t idx = (size_t)(blockIdx.x * 8 + node) * H + o;
    const float invn = 1.0f / (float)NN;
    float mu = stats[o] * invn;
    float var = stats[32 + o] * invn - mu * mu;
    float v = (z[idx] - mu) * rsqrtf(var + EPSV) * gm[o] + bt[o];
    v = v > 0.f ? v : 0.f;
    sh[node][o] = v;
    hout[idx] = v;
    __syncthreads();
    float a = bc[o], bacc = 0.f;
#pragma unroll
    for (int i = 0; i < H; i++) {
        float hv = sh[node][i];
        a += hv * sWr[i * H + o];
        bacc += hv * sBn[i * H + o];
    }
    zout[idx] = a;
    uout[idx] = bacc;
}

// ---------------- fused BN+ReLU -> graph pool (last layer; h never stored) ----------------
__global__ void k_bn_pool(const float* __restrict__ z, const float* __restrict__ stats,
                          const float* __restrict__ gm, const float* __restrict__ bt,
                          const int* __restrict__ batch, float* __restrict__ gsum) {
    int idx = blockIdx.x * 256 + threadIdx.x;
    if (idx >= NN * H) return;
    int n = idx >> 5, o = idx & 31;
    const float invn = 1.0f / (float)NN;
    float mu = stats[o] * invn;
    float var = stats[32 + o] * invn - mu * mu;
    float v = (z[idx] - mu) * rsqrtf(var + EPSV) * gm[o] + bt[o];
    v = v > 0.f ? v : 0.f;
    atomicAdd(&gsum[(size_t)batch[n] * H + o], v);
}

// ---------------- head: gx -> lin2 -> relu -> lin3 ----------------
__global__ void k_head(const float* __restrict__ gsum, const float* __restrict__ cnt,
                       const float* __restrict__ W2, const float* __restrict__ b2,
                       const float* __restrict__ W3, const float* __restrict__ b3,
                       float* __restrict__ out) {
    __shared__ float sW2[H * 16];
    __shared__ float sW3[16];
    __shared__ float sb2[16];
    int t = threadIdx.x;
    for (int j = t; j < H * 16; j += 256) sW2[j] = W2[j];
    if (t < 16) { sW3[t] = W3[t]; sb2[t] = b2[t]; }
    __syncthreads();
    int g = blockIdx.x * 256 + t;
    if (g >= NG) return;
    float inv = 1.0f / fmaxf(cnt[g], 1.0f);
    float gx[H];
#pragma unroll
    for (int i = 0; i < H; i++) gx[i] = gsum[g * H + i] * inv;
    float o3 = b3[0];
#pragma unroll
    for (int j = 0; j < 16; j++) {
        float hh = sb2[j];
#pragma unroll
        for (int i = 0; i < H; i++) hh += gx[i] * sW2[i * 16 + j];
        hh = hh > 0.f ? hh : 0.f;
        o3 += hh * sW3[j];
    }
    out[g] = o3;
}

extern "C" void kernel_launch(void* const* d_in, const int* in_sizes, int n_in,
                              void* d_out, int out_size, void* d_ws, size_t ws_size,
                              hipStream_t stream) {
    const float* x      = (const float*)d_in[0];
    const float* eattr  = (const float*)d_in[1];
    const float* W_node = (const float*)d_in[2];
    const float* b_node = (const float*)d_in[3];
    const float* W_edge = (const float*)d_in[4];
    const float* b_edge = (const float*)d_in[5];
    const float* W_nn   = (const float*)d_in[6];
    const float* b_nn   = (const float*)d_in[7];
    const float* W_root = (const float*)d_in[8];
    const float* b_conv = (const float*)d_in[9];
    const float* gamma  = (const float*)d_in[10];
    const float* beta   = (const float*)d_in[11];
    const float* W2     = (const float*)d_in[12];
    const float* b2     = (const float*)d_in[13];
    const float* W3     = (const float*)d_in[14];
    const float* b3     = (const float*)d_in[15];
    const int* eidx     = (const int*)d_in[16];
    const int* batch    = (const int*)d_in[17];
    const int* src = eidx;
    const int* dst = eidx + NE;
    float* out = (float*)d_out;

    float* ws = (float*)d_ws;
    float* h    = ws;                        // NN*32
    float* z    = h + (size_t)NN * H;        // NN*32
    float* u    = z + (size_t)NN * H;        // NN*32
    float* agg  = u + (size_t)NN * H;        // NN*32
    float* stats = agg + (size_t)NN * H;     // 64 (adjacent to agg: single memset)
    float* ea   = stats + 64;                // NE*32
    float* Wt   = ea + (size_t)NE * FE2;     // 3*32768
    float* gsum = Wt + (size_t)NL * 32768;   // NG*32
    float* cnt  = gsum + (size_t)NG * H;     // NG (adjacent to gsum: single memset)
    int* ip     = (int*)(cnt + NG);
    int* deg    = ip;                        // NN
    int* rowptr = deg + NN;                  // NN+1
    int* cursor = rowptr + NN + 1;           // NN
    int* eid    = cursor + NN;               // NE
    int* bsum   = eid + NE;                  // 64
    int* boff   = bsum + 64;                 // 64

    // one-time prep
    k_prep_wt<<<(NL * H * 1024 + 255) / 256, 256, 0, stream>>>(W_nn, Wt);
    k_edge_emb<<<(NE + 7) / 8, 256, 0, stream>>>(eattr, W_edge, b_edge, ea);

    // CSR by src + graph counts
    hipMemsetAsync(deg, 0, NN * sizeof(int), stream);
    hipMemsetAsync(gsum, 0, ((size_t)NG * H + NG) * sizeof(float), stream);
    k_deg_cnt<<<(NE + 255) / 256, 256, 0, stream>>>(src, deg, batch, cnt);
    k_scan1<<<49, 1024, 0, stream>>>(deg, rowptr, bsum);
    k_scan2<<<1, 64, 0, stream>>>(bsum, boff, rowptr);
    k_scan3<<<49, 1024, 0, stream>>>(rowptr, boff, cursor);
    k_fill<<<(NE + 255) / 256, 256, 0, stream>>>(src, cursor, eid);

    // node embedding + layer-0 node linear
    k_emb_lin<<<NN / 8, 256, 0, stream>>>(x, W_node, b_node, W_root, b_conv, b_nn,
                                          h, z, u);

    for (int l = 0; l < NL; l++) {
        hipMemsetAsync(agg, 0, ((size_t)NN * H + 64) * sizeof(float), stream);
        k_conv<<<NN / 8, 256, 0, stream>>>(h, u, ea, Wt + (size_t)l * 32768,
                                           rowptr, eid, src, dst, agg);
        k_add_stats<<<512, 256, 0, stream>>>(z, agg, stats);
        if (l < NL - 1) {
            k_bn_lin<<<NN / 8, 256, 0, stream>>>(z, stats, gamma + l * H, beta + l * H,
                                                 W_root + (l + 1) * H * H,
                                                 b_conv + (l + 1) * H,
                                                 b_nn + (size_t)(l + 1) * H * H,
                                                 h, z, u);
        } else {
            k_bn_pool<<<(NN * H + 255) / 256, 256, 0, stream>>>(z, stats, gamma + l * H,
                                                                beta + l * H, batch, gsum);
        }
    }

    k_head<<<(NG + 255) / 256, 256, 0, stream>>>(gsum, cnt, W2, b2, W3, b3, out);
}